// Round 10
// baseline (162.053 us; speedup 1.0000x reference)
//
#include <hip/hip_runtime.h>
#include <hip/hip_bf16.h>

// B=16, T_EN=256, T_DE=256, D=512, UNITS=128
// tanh(x) = (1-e)/(1+e), e = exp(-2x) = Een*Ede where E = 2^(-(2/ln2)*att).
// nu*tanh = 2nu/(1+e) - nu ; the -nu term is constant over the softmax axis
// (encoder i) and cancels. Pairwise combine (one rcp per TWO u-terms):
//   2n0/(1+e0)+2n1/(1+e1) = [2n0+2n1 + 2n0*e1 + 2n1*e0] * rcp((1+e0)(1+e1))
#define TANH_SCALE 2.8853900817779268f   // 2/ln(2)

// ws layout:
//   Ete [16 b][64 u2][256 i][2] f32 (2 MB)  en-side E, transposed pair-interleaved
//   Ede [4096 row][128 u]       f32 (2 MB)  de-side E, row-major
//   P   [2 mat][2 kq][4096][128] f32 (8 MB) split-K partials (only if ws >= 12MB)

// ---------------- shared GEMM tile: 32 rows x 128 cols, k-range ------------
__device__ __forceinline__ void gemm_tile_32x128(
        const float* __restrict__ X, const float* __restrict__ W,
        int row0, int k0, int k1, int tid, float acc[4][4],
        float (*xt)[36], float (*wsh)[128]) {
    const int xs_r  = tid >> 4;            // 0..15 (+16)
    const int xs_k4 = (tid & 15) * 4;      // 0..60
    float4 xr[2], wr[8];

    auto g_load = [&](int kt) {
#pragma unroll
        for (int s = 0; s < 2; ++s)
            xr[s] = *reinterpret_cast<const float4*>(
                X + (size_t)(row0 + xs_r + 16 * s) * 512 + kt + xs_k4);
#pragma unroll
        for (int s = 0; s < 8; ++s) {
            int idx = tid + 256 * s;
            wr[s] = *reinterpret_cast<const float4*>(
                W + (size_t)(kt + (idx >> 5)) * 128 + (idx & 31) * 4);
        }
    };
    auto lds_store = [&]() {
        const int swz = ((xs_k4 >> 2) & 7) << 2;
#pragma unroll
        for (int s = 0; s < 2; ++s) {
            int r = (xs_r + 16 * s) ^ swz;
            xt[xs_k4 + 0][r] = xr[s].x;
            xt[xs_k4 + 1][r] = xr[s].y;
            xt[xs_k4 + 2][r] = xr[s].z;
            xt[xs_k4 + 3][r] = xr[s].w;
        }
#pragma unroll
        for (int s = 0; s < 8; ++s) {
            int idx = tid + 256 * s;
            *reinterpret_cast<float4*>(&wsh[idx >> 5][(idx & 31) * 4]) = wr[s];
        }
    };

    const int tr = tid >> 5, tc = tid & 31;
    g_load(k0);
    lds_store();
    __syncthreads();
    for (int kt = k0; kt < k1; kt += 64) {
        const bool has_next = (kt + 64) < k1;
        if (has_next) g_load(kt + 64);
#pragma unroll
        for (int k = 0; k < 64; ++k) {
            const int col = (tr * 4) ^ (((k >> 2) & 7) << 2);
            float4 xv = *reinterpret_cast<const float4*>(&xt[k][col]);
            float4 wv = *reinterpret_cast<const float4*>(&wsh[k][tc * 4]);
            acc[0][0] = fmaf(xv.x, wv.x, acc[0][0]);
            acc[0][1] = fmaf(xv.x, wv.y, acc[0][1]);
            acc[0][2] = fmaf(xv.x, wv.z, acc[0][2]);
            acc[0][3] = fmaf(xv.x, wv.w, acc[0][3]);
            acc[1][0] = fmaf(xv.y, wv.x, acc[1][0]);
            acc[1][1] = fmaf(xv.y, wv.y, acc[1][1]);
            acc[1][2] = fmaf(xv.y, wv.z, acc[1][2]);
            acc[1][3] = fmaf(xv.y, wv.w, acc[1][3]);
            acc[2][0] = fmaf(xv.z, wv.x, acc[2][0]);
            acc[2][1] = fmaf(xv.z, wv.y, acc[2][1]);
            acc[2][2] = fmaf(xv.z, wv.z, acc[2][2]);
            acc[2][3] = fmaf(xv.z, wv.w, acc[2][3]);
            acc[3][0] = fmaf(xv.w, wv.x, acc[3][0]);
            acc[3][1] = fmaf(xv.w, wv.y, acc[3][1]);
            acc[3][2] = fmaf(xv.w, wv.z, acc[3][2]);
            acc[3][3] = fmaf(xv.w, wv.w, acc[3][3]);
        }
        __syncthreads();
        if (has_next) {
            lds_store();
            __syncthreads();
        }
    }
}

// ---------------- K1a: split-K GEMM partials (ws >= 12MB path) -------------
// grid (128 rowtiles, 2 mat, 2 khalf) x 256 thr; 512 blocks = 2/CU.
__global__ __launch_bounds__(256) void proj_split_kernel(
        const float* __restrict__ en, const float* __restrict__ de,
        const float* __restrict__ w_en, const float* __restrict__ w_de,
        float* __restrict__ P) {
    __shared__ float xt[64][36];
    __shared__ float wsh[64][128];
    const bool is_en = (blockIdx.y == 0);
    const float* X = is_en ? en : de;
    const float* W = is_en ? w_en : w_de;
    const int row0 = blockIdx.x * 32;
    const int kq   = blockIdx.z;

    float acc[4][4] = {{0.f}};
    gemm_tile_32x128(X, W, row0, kq * 256, kq * 256 + 256, threadIdx.x,
                     acc, xt, wsh);

    float* OUT = P + (size_t)(blockIdx.y * 2 + kq) * 524288;
    const int tr = threadIdx.x >> 5, tc = threadIdx.x & 31;
#pragma unroll
    for (int r = 0; r < 4; ++r)
        *reinterpret_cast<float4*>(OUT + (size_t)(row0 + tr * 4 + r) * 128 + tc * 4)
            = make_float4(acc[r][0], acc[r][1], acc[r][2], acc[r][3]);
}

// ---------------- K1b: combine partials -> E with layouts ------------------
// grid (512, 2) x 256. gid covers 4096 rows x 32 float4.
__global__ __launch_bounds__(256) void combine_kernel(
        const float* __restrict__ P, float* __restrict__ Ete,
        float* __restrict__ Ede) {
    const int gid = blockIdx.x * 256 + threadIdx.x;   // 0..131071
    const float* Pm = P + (size_t)blockIdx.y * 1048576;
    float4 a = reinterpret_cast<const float4*>(Pm)[gid];
    float4 b = reinterpret_cast<const float4*>(Pm + 524288)[gid];
    float4 v;
    v.x = __builtin_exp2f(-TANH_SCALE * (a.x + b.x));
    v.y = __builtin_exp2f(-TANH_SCALE * (a.y + b.y));
    v.z = __builtin_exp2f(-TANH_SCALE * (a.z + b.z));
    v.w = __builtin_exp2f(-TANH_SCALE * (a.w + b.w));
    if (blockIdx.y == 1) {
        reinterpret_cast<float4*>(Ede)[gid] = v;
    } else {
        const int row = gid >> 5, u4 = gid & 31;
        const int b_ = row >> 8, i = row & 255;
        float* base = Ete + (size_t)b_ * 32768 + (size_t)(u4 * 2) * 512 + i * 2;
        *reinterpret_cast<float2*>(base)       = make_float2(v.x, v.y);
        *reinterpret_cast<float2*>(base + 512) = make_float2(v.z, v.w);
    }
}

// ---------------- K1 fallback: single-kernel proj (small ws) ---------------
__global__ __launch_bounds__(256) void proj_full_kernel(
        const float* __restrict__ en, const float* __restrict__ de,
        const float* __restrict__ w_en, const float* __restrict__ w_de,
        float* __restrict__ Ete, float* __restrict__ Ede) {
    __shared__ float xt[64][36];
    __shared__ float wsh[64][128];
    const bool is_en = (blockIdx.y == 0);
    const float* X = is_en ? en : de;
    const float* W = is_en ? w_en : w_de;
    const int row0 = blockIdx.x * 32;

    float acc[4][4] = {{0.f}};
    gemm_tile_32x128(X, W, row0, 0, 512, threadIdx.x, acc, xt, wsh);

    const int tr = threadIdx.x >> 5, tc = threadIdx.x & 31;
    float v[4][4];
#pragma unroll
    for (int r = 0; r < 4; ++r)
#pragma unroll
        for (int c = 0; c < 4; ++c)
            v[r][c] = __builtin_exp2f(-TANH_SCALE * acc[r][c]);

    if (!is_en) {
#pragma unroll
        for (int r = 0; r < 4; ++r)
            *reinterpret_cast<float4*>(
                Ede + (size_t)(row0 + tr * 4 + r) * 128 + tc * 4) =
                make_float4(v[r][0], v[r][1], v[r][2], v[r][3]);
    } else {
        const int b_ = row0 >> 8;
        const int il0 = (row0 & 255) + tr * 4;
#pragma unroll
        for (int cp = 0; cp < 2; ++cp) {
            size_t base = (size_t)b_ * 32768 + (size_t)(tc * 2 + cp) * 512 + il0 * 2;
            *reinterpret_cast<float4*>(Ete + base) =
                make_float4(v[0][2 * cp], v[0][2 * cp + 1],
                            v[1][2 * cp], v[1][2 * cp + 1]);
            *reinterpret_cast<float4*>(Ete + base + 4) =
                make_float4(v[2][2 * cp], v[2][2 * cp + 1],
                            v[3][2 * cp], v[3][2 * cp + 1]);
        }
    }
}

// ---------------- K2: fused mu + softmax + PV + de-copy ---------------------
// 512 blocks x 512 threads. Block = (b, j-tile of 8 decoder rows).
// Phase A reads Ete coalesced (lane = i, float2 per u-pair) with 1-iter
// register prefetch; pairwise-rational inner (reg-light: round-5 lesson).
__global__ __launch_bounds__(512, 4) void fused_attn_kernel(
        const float* __restrict__ Ete, const float* __restrict__ Ede,
        const float* __restrict__ nu, const float* __restrict__ en,
        const float* __restrict__ de, float* __restrict__ out) {
    const int phys = blockIdx.x;
    const int lid  = (phys & 7) * 64 + (phys >> 3);   // XCD swizzle (512%8==0)
    const int b    = lid >> 5;          // 0..15
    const int j0   = (lid & 31) * 8;    // 0..248
    const int tid  = threadIdx.x;
    const int i    = tid & 255;
    const int uh   = tid >> 8;          // 0/1

    __shared__ float ede_sh[8][128];
    __shared__ float nu2_sh[128];       // 2*nu
    __shared__ float nusum_sh[64];      // 2*(nu[2p]+nu[2p+1])
    __shared__ float al[8][256];
    __shared__ float red[8][4];

    if (tid < 256)
        reinterpret_cast<float4*>(&ede_sh[0][0])[tid] =
            reinterpret_cast<const float4*>(Ede + ((size_t)b * 256 + j0) * 128)[tid];
    if (tid >= 256 && tid < 384) nu2_sh[tid - 256] = 2.0f * nu[tid - 256];
    if (tid >= 384 && tid < 448) {
        int t = tid - 384;
        nusum_sh[t] = 2.0f * (nu[2 * t] + nu[2 * t + 1]);
    }

    // de_seq copy into left half of out (overlaps everything)
    {
        const float4* dsrc =
            reinterpret_cast<const float4*>(de + ((size_t)b * 256 + j0) * 512);
#pragma unroll
        for (int t = 0; t < 2; ++t) {
            int idx = tid + 512 * t;
            int j = idx >> 7, c4 = idx & 127;
            reinterpret_cast<float4*>(out + (size_t)(b * 256 + j0 + j) * 1024)[c4] =
                dsrc[idx];
        }
    }
    __syncthreads();

    // ---- phase A: s[jl] = sum_u 2nu[u] / (1 + Een[i][u]*Ede[j][u]) ----
    float s[4] = {0.0f, 0.0f, 0.0f, 0.0f};
    const float2* ep =
        reinterpret_cast<const float2*>(Ete) + (size_t)b * 16384 + i;
    const float4* nu4 = reinterpret_cast<const float4*>(nu2_sh);
    const float4* cs4 = reinterpret_cast<const float4*>(nusum_sh);

    float2 evc[4], evn[4];
#pragma unroll
    for (int t = 0; t < 4; ++t) evc[t] = ep[t * 256];
    for (int q = 0; q < 16; ++q) {      // 8 u per iter; NOT unrolled (VGPR)
        if (q < 15) {
#pragma unroll
            for (int t = 0; t < 4; ++t) evn[t] = ep[(4 * (q + 1) + t) * 256];
        }
        const float4 na = nu4[2 * q];
        const float4 nb = nu4[2 * q + 1];
        const float4 cs = cs4[q];
#pragma unroll
        for (int jl = 0; jl < 4; ++jl) {
            const float* dr = &ede_sh[uh * 4 + jl][8 * q];
            const float4 da = *reinterpret_cast<const float4*>(dr);
            const float4 db = *reinterpret_cast<const float4*>(dr + 4);
            float e0, e1, den, num;
            e0 = evc[0].x * da.x; e1 = evc[0].y * da.y;
            den = 1.0f + e0; den = fmaf(den, e1, den);
            num = fmaf(na.x, e1, cs.x); num = fmaf(na.y, e0, num);
            s[jl] = fmaf(num, __builtin_amdgcn_rcpf(den), s[jl]);
            e0 = evc[1].x * da.z; e1 = evc[1].y * da.w;
            den = 1.0f + e0; den = fmaf(den, e1, den);
            num = fmaf(na.z, e1, cs.y); num = fmaf(na.w, e0, num);
            s[jl] = fmaf(num, __builtin_amdgcn_rcpf(den), s[jl]);
            e0 = evc[2].x * db.x; e1 = evc[2].y * db.y;
            den = 1.0f + e0; den = fmaf(den, e1, den);
            num = fmaf(nb.x, e1, cs.z); num = fmaf(nb.y, e0, num);
            s[jl] = fmaf(num, __builtin_amdgcn_rcpf(den), s[jl]);
            e0 = evc[3].x * db.z; e1 = evc[3].y * db.w;
            den = 1.0f + e0; den = fmaf(den, e1, den);
            num = fmaf(nb.z, e1, cs.w); num = fmaf(nb.w, e0, num);
            s[jl] = fmaf(num, __builtin_amdgcn_rcpf(den), s[jl]);
        }
        if (q < 15) {
#pragma unroll
            for (int t = 0; t < 4; ++t) evc[t] = evn[t];
        }
    }

    // ---- phase B: softmax over i (Sum(nu) shift cancels; exp safe) ----
    float p[4];
#pragma unroll
    for (int jl = 0; jl < 4; ++jl) p[jl] = __expf(s[jl]);
    const int lane = tid & 63;
    const int w    = (tid >> 6) & 3;
#pragma unroll
    for (int jl = 0; jl < 4; ++jl) {
        float t = p[jl];
#pragma unroll
        for (int off = 32; off >= 1; off >>= 1) t += __shfl_xor(t, off);
        if (lane == 0) red[uh * 4 + jl][w] = t;
    }
    __syncthreads();
#pragma unroll
    for (int jl = 0; jl < 4; ++jl) {
        const int j = uh * 4 + jl;
        float T = red[j][0] + red[j][1] + red[j][2] + red[j][3];
        al[j][i] = p[jl] * __builtin_amdgcn_rcpf(T);
    }
    __syncthreads();

    // ---- phase C: sum_en[j][c] = sum_i al[j][i] * en[b][i][c], c = tid ----
    float acc[8];
#pragma unroll
    for (int j = 0; j < 8; ++j) acc[j] = 0.0f;
    const float* enb = en + (size_t)b * 256 * 512;
    const int c = tid;
    for (int i0 = 0; i0 < 256; i0 += 4) {
        float a[8][4];
#pragma unroll
        for (int j = 0; j < 8; ++j) {
            float4 v = *reinterpret_cast<const float4*>(&al[j][i0]);  // broadcast
            a[j][0] = v.x; a[j][1] = v.y; a[j][2] = v.z; a[j][3] = v.w;
        }
#pragma unroll
        for (int ii = 0; ii < 4; ++ii) {
            float e0 = enb[(size_t)(i0 + ii) * 512 + c];
#pragma unroll
            for (int j = 0; j < 8; ++j)
                acc[j] = fmaf(a[j][ii], e0, acc[j]);
        }
    }
#pragma unroll
    for (int j = 0; j < 8; ++j) {
        size_t row = (size_t)(b * 256 + j0 + j);
        out[row * 1024 + 512 + c] = acc[j];
    }
}

extern "C" void kernel_launch(void* const* d_in, const int* in_sizes, int n_in,
                              void* d_out, int out_size, void* d_ws, size_t ws_size,
                              hipStream_t stream) {
    const float* en   = (const float*)d_in[0];  // (16,256,512)
    const float* de   = (const float*)d_in[1];  // (16,256,512)
    const float* w_en = (const float*)d_in[2];  // (512,128)
    const float* w_de = (const float*)d_in[3];  // (512,128)
    const float* nu   = (const float*)d_in[4];  // (128,1)
    float* out = (float*)d_out;                 // (16,256,1024)

    char* ws = (char*)d_ws;
    float* Ete = (float*)(ws);                            // 2 MB
    float* Ede = (float*)(ws + (size_t)2 * 1024 * 1024);  // 2 MB
    float* P   = (float*)(ws + (size_t)4 * 1024 * 1024);  // 8 MB (split path)

    const bool split = ws_size >= (size_t)12 * 1024 * 1024;  // launch-constant
    if (split) {
        proj_split_kernel<<<dim3(128, 2, 2), 256, 0, stream>>>(
            en, de, w_en, w_de, P);
        combine_kernel<<<dim3(512, 2), 256, 0, stream>>>(P, Ete, Ede);
    } else {
        proj_full_kernel<<<dim3(128, 2), 256, 0, stream>>>(
            en, de, w_en, w_de, Ete, Ede);
    }
    fused_attn_kernel<<<dim3(512), 512, 0, stream>>>(Ete, Ede, nu, en, de, out);
}